// Round 1
// baseline (419.830 us; speedup 1.0000x reference)
//
#include <hip/hip_runtime.h>
#include <hip/hip_bf16.h>
#include <cstddef>

// Problem constants
#define BATCH 2
#define SEQ   1024
#define DMODEL 1024
#define NHEADS 16
#define DHEAD 64
#define E3D   3072
#define NCHUNK 16   // chunks of 64 positions along S
#define CHUNK 64

// beta (normalized), nonzero only for p=1..5 (T1..T5)
#define BETA1 0.45736626f
#define BETA2 0.26218724f
#define BETA3 0.15594524f
#define BETA4 0.08693904f
#define BETA5 0.03756222f

__device__ __forceinline__ void cheb5(float x, float T[6]) {
    T[0] = 1.f; T[1] = x;
    float tx2 = 2.f * x;
    T[2] = tx2 * T[1] - T[0];
    T[3] = tx2 * T[2] - T[1];
    T[4] = tx2 * T[3] - T[2];
    T[5] = tx2 * T[4] - T[3];
}

__device__ __forceinline__ float clampx(float v) {
    return fminf(fmaxf(v * 0.125f, -1.f + 1e-6f), 1.f - 1e-6f);
}

__device__ __forceinline__ float wave_sum(float x) {
#pragma unroll
    for (int m = 32; m >= 1; m >>= 1) x += __shfl_xor(x, m, 64);
    return x;
}

// ---------------------------------------------------------------------------
// GEMM: C[m,n] = sum_k A[m*K+k] * B[n*K+k]   (both K-contiguous, "TN" layout)
// 128x128 tile, BK=16, 256 threads, 8x8 microtile (2x2 blocks of float4).
// ---------------------------------------------------------------------------
#define GBM 128
#define GBN 128
#define GBK 16
#define LDP (GBM + 4)

__global__ __launch_bounds__(256) void gemm_tn(const float* __restrict__ A,
                                               const float* __restrict__ B,
                                               float* __restrict__ C,
                                               int M, int N, int K)
{
    __shared__ float As[GBK][LDP];
    __shared__ float Bs[GBK][LDP];

    const int tid = threadIdx.x;
    const int tx = tid & 15;   // n-dim
    const int ty = tid >> 4;   // m-dim
    const int m0 = blockIdx.y * GBM;
    const int n0 = blockIdx.x * GBN;

    float acc[8][8];
#pragma unroll
    for (int i = 0; i < 8; i++)
#pragma unroll
        for (int j = 0; j < 8; j++) acc[i][j] = 0.f;

    // staging: 512 float4 per tile, 2 per thread (rows r and r+64)
    const int r  = tid >> 2;
    const int c4 = (tid & 3) * 4;
    const float* pa0 = A + (size_t)(m0 + r) * K + c4;
    const float* pa1 = A + (size_t)(m0 + r + 64) * K + c4;
    const float* pb0 = B + (size_t)(n0 + r) * K + c4;
    const float* pb1 = B + (size_t)(n0 + r + 64) * K + c4;

    for (int k0 = 0; k0 < K; k0 += GBK) {
        float4 a0 = *(const float4*)(pa0 + k0);
        float4 a1 = *(const float4*)(pa1 + k0);
        float4 b0 = *(const float4*)(pb0 + k0);
        float4 b1 = *(const float4*)(pb1 + k0);
        __syncthreads();
        As[c4 + 0][r] = a0.x; As[c4 + 1][r] = a0.y; As[c4 + 2][r] = a0.z; As[c4 + 3][r] = a0.w;
        As[c4 + 0][r + 64] = a1.x; As[c4 + 1][r + 64] = a1.y; As[c4 + 2][r + 64] = a1.z; As[c4 + 3][r + 64] = a1.w;
        Bs[c4 + 0][r] = b0.x; Bs[c4 + 1][r] = b0.y; Bs[c4 + 2][r] = b0.z; Bs[c4 + 3][r] = b0.w;
        Bs[c4 + 0][r + 64] = b1.x; Bs[c4 + 1][r + 64] = b1.y; Bs[c4 + 2][r + 64] = b1.z; Bs[c4 + 3][r + 64] = b1.w;
        __syncthreads();
#pragma unroll
        for (int kk = 0; kk < GBK; kk++) {
            float4 aL = *(const float4*)&As[kk][ty * 4];
            float4 aH = *(const float4*)&As[kk][64 + ty * 4];
            float4 bL = *(const float4*)&Bs[kk][tx * 4];
            float4 bH = *(const float4*)&Bs[kk][64 + tx * 4];
            float av[8] = {aL.x, aL.y, aL.z, aL.w, aH.x, aH.y, aH.z, aH.w};
            float bv[8] = {bL.x, bL.y, bL.z, bL.w, bH.x, bH.y, bH.z, bH.w};
#pragma unroll
            for (int i = 0; i < 8; i++)
#pragma unroll
                for (int j = 0; j < 8; j++) acc[i][j] += av[i] * bv[j];
        }
    }

#pragma unroll
    for (int i = 0; i < 8; i++) {
        int mi = m0 + ((i < 4) ? (ty * 4 + i) : (64 + ty * 4 + i - 4));
        float4 lo = make_float4(acc[i][0], acc[i][1], acc[i][2], acc[i][3]);
        float4 hi = make_float4(acc[i][4], acc[i][5], acc[i][6], acc[i][7]);
        *(float4*)(C + (size_t)mi * N + n0 + tx * 4) = lo;
        *(float4*)(C + (size_t)mi * N + n0 + 64 + tx * 4) = hi;
    }
}

// ---------------------------------------------------------------------------
// Attention part. qkv layout: [b*S+s][3072], q at h*64+d, k at +1024, v at +2048
// ---------------------------------------------------------------------------

// Per-position head-sums of Tq (beta-folded) and Tk. One wave per position.
__global__ __launch_bounds__(256) void k_sums(const float* __restrict__ qkv,
                                              float* __restrict__ SQB,
                                              float* __restrict__ SK)
{
    const int lane = threadIdx.x & 63;
    const int pos  = blockIdx.x * 4 + (threadIdx.x >> 6);  // (bh, s) flattened
    const int bh = pos >> 10, s = pos & 1023;
    const int b = bh >> 4, h = bh & 15;
    const float* base = qkv + (size_t)(b * SEQ + s) * E3D + h * DHEAD + lane;
    float xq = clampx(base[0]);
    float xk = clampx(base[1024]);
    float Tq[6], Tk[6];
    cheb5(xq, Tq); cheb5(xk, Tk);
    const float BETA[5] = {BETA1, BETA2, BETA3, BETA4, BETA5};
#pragma unroll
    for (int p = 1; p <= 5; p++) {
        float sq = wave_sum(Tq[p]);
        float sk = wave_sum(Tk[p]);
        if (lane == 0) {
            SQB[(size_t)pos * 5 + p - 1] = sq * BETA[p - 1];
            SK[(size_t)pos * 5 + p - 1]  = sk;
        }
    }
}

// Chunk sums of SK + exclusive prefix over chunks. One block per (b,h).
__global__ __launch_bounds__(128) void k_denprefix(const float* __restrict__ SK,
                                                   float* __restrict__ SKP)
{
    __shared__ float sums[NCHUNK][5];
    const int bh = blockIdx.x;
    const int t = threadIdx.x;
    if (t < NCHUNK * 5) {
        const int chunk = t / 5, p = t % 5;
        float s = 0.f;
        const float* base = SK + ((size_t)bh * SEQ + chunk * CHUNK) * 5 + p;
        for (int i = 0; i < CHUNK; i++) s += base[i * 5];
        sums[chunk][p] = s;
    }
    __syncthreads();
    if (t < 5) {
        float run = 0.f;
        for (int c = 0; c < NCHUNK; c++) {
            SKP[(size_t)(bh * NCHUNK + c) * 5 + t] = run;
            run += sums[c][t];
        }
    }
}

// den[s] = sum_p SQB[s,p] * (SKP_base[p] + inclusive_prefix_in_chunk(SK[.,p]))
__global__ __launch_bounds__(64) void k_den(const float* __restrict__ SK,
                                            const float* __restrict__ SKP,
                                            const float* __restrict__ SQB,
                                            float* __restrict__ DEN)
{
    const int lane = threadIdx.x;                 // position within chunk
    const int blk = blockIdx.x;                   // bh*16 + chunk
    const int bh = blk >> 4, chunk = blk & 15;
    const int pos = bh * SEQ + chunk * CHUNK + lane;
    float den = 0.f;
#pragma unroll
    for (int p = 0; p < 5; p++) {
        float x = SK[(size_t)pos * 5 + p];
#pragma unroll
        for (int off = 1; off < 64; off <<= 1) {
            float n = __shfl_up(x, off, 64);
            if (lane >= off) x += n;
        }
        float ks = SKP[(size_t)blk * 5 + p] + x;
        den += SQB[(size_t)pos * 5 + p] * ks;
    }
    DEN[pos] = den;
}

// Chunk totals of kv = sum_s Tk[p,d]*v[d]. One wave per (b,h,chunk), lane = d.
__global__ __launch_bounds__(64) void k_kvchunk(const float* __restrict__ qkv,
                                                float* __restrict__ KVC)
{
    const int lane = threadIdx.x;
    const int blk = blockIdx.x;
    const int bh = blk >> 4, chunk = blk & 15;
    const int b = bh >> 4, h = bh & 15;
    const float* kb = qkv + (size_t)(b * SEQ + chunk * CHUNK) * E3D + 1024 + h * DHEAD + lane;
    float kv[5] = {0.f, 0.f, 0.f, 0.f, 0.f};
    for (int i = 0; i < CHUNK; i++) {
        const float* row = kb + (size_t)i * E3D;
        float xk = clampx(row[0]);
        float v = row[1024];
        float T[6]; cheb5(xk, T);
#pragma unroll
        for (int p = 1; p <= 5; p++) kv[p - 1] += T[p] * v;
    }
#pragma unroll
    for (int p = 0; p < 5; p++) KVC[((size_t)blk * 5 + p) * 64 + lane] = kv[p];
}

// Exclusive prefix over chunks for kv state, in place. One thread per (bh,p,d).
__global__ void k_kvprefix(float* __restrict__ KVC)
{
    const int id = blockIdx.x * 256 + threadIdx.x;
    if (id >= BATCH * NHEADS * 5 * 64) return;
    const int bh = id / 320, rem = id % 320;
    float run = 0.f;
    for (int c = 0; c < NCHUNK; c++) {
        size_t idx = (size_t)(bh * NCHUNK + c) * 320 + rem;
        float t = KVC[idx];
        KVC[idx] = run;
        run += t;
    }
}

// Final per-position output: scan kv within chunk, num/den. Lane = d.
__global__ __launch_bounds__(64) void k_out(const float* __restrict__ qkv,
                                            const float* __restrict__ KVC,
                                            const float* __restrict__ DEN,
                                            float* __restrict__ OUTH)
{
    const int lane = threadIdx.x;
    const int blk = blockIdx.x;
    const int bh = blk >> 4, chunk = blk & 15;
    const int b = bh >> 4, h = bh & 15;
    const float BETA[5] = {BETA1, BETA2, BETA3, BETA4, BETA5};
    float kv[5];
#pragma unroll
    for (int p = 0; p < 5; p++) kv[p] = KVC[((size_t)blk * 5 + p) * 64 + lane];
    const float* qb = qkv + (size_t)(b * SEQ + chunk * CHUNK) * E3D + h * DHEAD + lane;
    float* ob = OUTH + (size_t)(b * SEQ + chunk * CHUNK) * DMODEL + h * DHEAD + lane;
    for (int i = 0; i < CHUNK; i++) {
        const float* row = qb + (size_t)i * E3D;
        float xq = clampx(row[0]);
        float xk = clampx(row[1024]);
        float v = row[2048];
        float Tk_[6]; cheb5(xk, Tk_);
#pragma unroll
        for (int p = 1; p <= 5; p++) kv[p - 1] += Tk_[p] * v;
        float Tq_[6]; cheb5(xq, Tq_);
        float num = 0.f;
#pragma unroll
        for (int p = 1; p <= 5; p++) num += BETA[p - 1] * Tq_[p] * kv[p - 1];
        float den = DEN[(size_t)bh * SEQ + chunk * CHUNK + i];
        ob[(size_t)i * DMODEL] = num / (den + 1e-7f);
    }
}

// ---------------------------------------------------------------------------

extern "C" void kernel_launch(void* const* d_in, const int* in_sizes, int n_in,
                              void* d_out, int out_size, void* d_ws, size_t ws_size,
                              hipStream_t stream)
{
    const float* x    = (const float*)d_in[0];  // (2,1024,1024)
    const float* Win  = (const float*)d_in[1];  // (3072,1024)
    const float* Wout = (const float*)d_in[2];  // (1024,1024)
    float* out = (float*)d_out;                 // (2,1024,1024)
    float* ws = (float*)d_ws;

    // workspace layout (floats)
    float* QKV  = ws;                 // 2048*3072       = 6291456
    float* OUTH = ws + 6291456;       // 2048*1024       = 2097152
    float* SQB  = ws + 8388608;       // 32*1024*5       = 163840
    float* SK   = ws + 8552448;       // 32*1024*5       = 163840
    float* SKP  = ws + 8716288;       // 32*16*5         = 2560
    float* DEN  = ws + 8718848;       // 32*1024         = 32768
    float* KVC  = ws + 8751616;       // 32*16*5*64      = 163840
    // total 8915456 floats = ~35.7 MB

    // 1) QKV projection: qkv = x @ W_in^T   (M=2048, N=3072, K=1024)
    dim3 g1(E3D / GBN, (BATCH * SEQ) / GBM);
    gemm_tn<<<g1, 256, 0, stream>>>(x, Win, QKV, BATCH * SEQ, E3D, DMODEL);

    // 2) attention scans
    k_sums<<<(BATCH * NHEADS * SEQ) / 4, 256, 0, stream>>>(QKV, SQB, SK);
    k_denprefix<<<BATCH * NHEADS, 128, 0, stream>>>(SK, SKP);
    k_den<<<BATCH * NHEADS * NCHUNK, 64, 0, stream>>>(SK, SKP, SQB, DEN);
    k_kvchunk<<<BATCH * NHEADS * NCHUNK, 64, 0, stream>>>(QKV, KVC);
    k_kvprefix<<<40, 256, 0, stream>>>(KVC);
    k_out<<<BATCH * NHEADS * NCHUNK, 64, 0, stream>>>(QKV, KVC, DEN, OUTH);

    // 3) output projection: out = out_h @ W_out^T  (M=2048, N=1024, K=1024)
    dim3 g2(DMODEL / GBN, (BATCH * SEQ) / GBM);
    gemm_tn<<<g2, 256, 0, stream>>>(OUTH, Wout, out, BATCH * SEQ, DMODEL, DMODEL);
}

// Round 2
// 275.755 us; speedup vs baseline: 1.5225x; 1.5225x over previous
//
#include <hip/hip_runtime.h>
#include <hip/hip_bf16.h>
#include <cstddef>
#include <cstdint>

// Problem constants
#define BATCH 2
#define SEQ   1024
#define DMODEL 1024
#define NHEADS 16
#define DHEAD 64
#define E3D   3072
#define NCHUNK 16   // chunks of 64 positions along S
#define CHUNK 64

// beta (normalized), nonzero only for p=1..5 (T1..T5)
#define BETA1 0.45736626f
#define BETA2 0.26218724f
#define BETA3 0.15594524f
#define BETA4 0.08693904f
#define BETA5 0.03756222f

typedef __attribute__((ext_vector_type(8))) short short8;
typedef __attribute__((ext_vector_type(4))) float floatx4;

__device__ __forceinline__ unsigned short f2bf(float f) {
    unsigned u = __float_as_uint(f);
    u += 0x7fffu + ((u >> 16) & 1u);   // round-to-nearest-even
    return (unsigned short)(u >> 16);
}
__device__ __forceinline__ float bf2f(unsigned short h) {
    return __uint_as_float(((unsigned)h) << 16);
}

__device__ __forceinline__ void cp16(const void* g, void* l) {
    __builtin_amdgcn_global_load_lds(
        (const __attribute__((address_space(1))) void*)(uintptr_t)g,
        (__attribute__((address_space(3))) void*)(uintptr_t)l,
        16, 0, 0);
}

__device__ __forceinline__ void cheb5(float x, float T[6]) {
    T[0] = 1.f; T[1] = x;
    float tx2 = 2.f * x;
    T[2] = tx2 * T[1] - T[0];
    T[3] = tx2 * T[2] - T[1];
    T[4] = tx2 * T[3] - T[2];
    T[5] = tx2 * T[4] - T[3];
}

__device__ __forceinline__ float clampx(float v) {
    return fminf(fmaxf(v * 0.125f, -1.f + 1e-6f), 1.f - 1e-6f);
}

__device__ __forceinline__ float wave_sum(float x) {
#pragma unroll
    for (int m = 32; m >= 1; m >>= 1) x += __shfl_xor(x, m, 64);
    return x;
}

// ---------------------------------------------------------------------------
// Split fp32 -> 3x bf16 (hi, mid, lo), RNE at each level.
// ---------------------------------------------------------------------------
__global__ __launch_bounds__(256) void k_split3(const float* __restrict__ in,
                                                unsigned short* __restrict__ h,
                                                unsigned short* __restrict__ m,
                                                unsigned short* __restrict__ l,
                                                int n4)
{
    int i = blockIdx.x * 256 + threadIdx.x;
    if (i >= n4) return;
    float4 v = ((const float4*)in)[i];
    float vv[4] = {v.x, v.y, v.z, v.w};
    unsigned short hh[4], mm[4], ll[4];
#pragma unroll
    for (int j = 0; j < 4; j++) {
        unsigned short a = f2bf(vv[j]); float r1 = vv[j] - bf2f(a);
        unsigned short b = f2bf(r1);    float r2 = r1 - bf2f(b);
        hh[j] = a; mm[j] = b; ll[j] = f2bf(r2);
    }
    ((ushort4*)h)[i] = make_ushort4(hh[0], hh[1], hh[2], hh[3]);
    ((ushort4*)m)[i] = make_ushort4(mm[0], mm[1], mm[2], mm[3]);
    ((ushort4*)l)[i] = make_ushort4(ll[0], ll[1], ll[2], ll[3]);
}

// ---------------------------------------------------------------------------
// Split-bf16 MFMA GEMM: C[m,n] = sum_k A[m,k]*B[n,k], A,B given as 3-way bf16
// splits (K-major). 128x128 tile, BK=32, 256 threads = 4 waves, each wave a
// 4x4 grid of 16x16x32 MFMA tiles. global_load_lds staging with XOR segment
// swizzle: LDS row r, position p holds global segment s = p ^ ((r>>1)&3)
// -> frag ds_read_b128 lands 2 lanes/bank (free).
// ---------------------------------------------------------------------------
__global__ __launch_bounds__(256) void gemm_split3(
    const unsigned short* __restrict__ Ah, const unsigned short* __restrict__ Am,
    const unsigned short* __restrict__ Al,
    const unsigned short* __restrict__ Bh, const unsigned short* __restrict__ Bm,
    const unsigned short* __restrict__ Bl,
    float* __restrict__ C, int M, int N, int K)
{
    __shared__ unsigned short lds[6 * 4096];   // Ah,Am,Al,Bh,Bm,Bl tiles: 128x32 each

    const int tid  = threadIdx.x;
    const int w    = tid >> 6;
    const int lane = tid & 63;
    const int m0 = blockIdx.y * 128;
    const int n0 = blockIdx.x * 128;

    // staging addresses: lane i covers tile-row r, seg-position p=(i&3);
    // fetch global segment s = p ^ ((r>>1)&3)
    const int r0 = w * 32 + (lane >> 2);
    const int r1 = r0 + 16;
    const int s0 = (lane & 3) ^ ((r0 >> 1) & 3);
    const int s1 = (lane & 3) ^ ((r1 >> 1) & 3);
    const size_t offA0 = (size_t)(m0 + r0) * K + s0 * 8;
    const size_t offA1 = (size_t)(m0 + r1) * K + s1 * 8;
    const size_t offB0 = (size_t)(n0 + r0) * K + s0 * 8;
    const size_t offB1 = (size_t)(n0 + r1) * K + s1 * 8;
    const int ldsRow0 = (w * 32) * 32;        // element offset of this wave's 16-row group
    const int ldsRow1 = (w * 32 + 16) * 32;

    const unsigned short* gA[3] = {Ah, Am, Al};
    const unsigned short* gB[3] = {Bh, Bm, Bl};

    // fragment read addresses
    const int q = lane >> 4, l16 = lane & 15;
    const int wm = w & 1, wn = w >> 1;
    const int ra = wm * 64 + l16;
    const int rb = wn * 64 + l16;
    const int aadr = ra * 32 + ((q ^ ((ra >> 1) & 3)) * 8);
    const int badr = rb * 32 + ((q ^ ((rb >> 1) & 3)) * 8);

    floatx4 acc[4][4] = {};

    for (int k0 = 0; k0 < K; k0 += 32) {
        __syncthreads();  // previous iteration's frag reads done before overwrite
#pragma unroll
        for (int b = 0; b < 3; b++) {
            cp16(gA[b] + offA0 + k0, &lds[b * 4096 + ldsRow0]);
            cp16(gA[b] + offA1 + k0, &lds[b * 4096 + ldsRow1]);
            cp16(gB[b] + offB0 + k0, &lds[(b + 3) * 4096 + ldsRow0]);
            cp16(gB[b] + offB1 + k0, &lds[(b + 3) * 4096 + ldsRow1]);
        }
        __syncthreads();  // staged data visible (compiler drains vmcnt before barrier)

        short8 fah[4], fam[4], fal[4], fbh[4], fbm[4], fbl[4];
#pragma unroll
        for (int t = 0; t < 4; t++) {
            fah[t] = *(const short8*)&lds[aadr + t * 512];
            fam[t] = *(const short8*)&lds[4096  + aadr + t * 512];
            fal[t] = *(const short8*)&lds[8192  + aadr + t * 512];
            fbh[t] = *(const short8*)&lds[12288 + badr + t * 512];
            fbm[t] = *(const short8*)&lds[16384 + badr + t * 512];
            fbl[t] = *(const short8*)&lds[20480 + badr + t * 512];
        }
#pragma unroll
        for (int mt = 0; mt < 4; mt++)
#pragma unroll
            for (int nt = 0; nt < 4; nt++) {
                floatx4 c = acc[mt][nt];
                c = __builtin_amdgcn_mfma_f32_16x16x32_bf16(fah[mt], fbh[nt], c, 0, 0, 0);
                c = __builtin_amdgcn_mfma_f32_16x16x32_bf16(fah[mt], fbm[nt], c, 0, 0, 0);
                c = __builtin_amdgcn_mfma_f32_16x16x32_bf16(fam[mt], fbh[nt], c, 0, 0, 0);
                c = __builtin_amdgcn_mfma_f32_16x16x32_bf16(fah[mt], fbl[nt], c, 0, 0, 0);
                c = __builtin_amdgcn_mfma_f32_16x16x32_bf16(fal[mt], fbh[nt], c, 0, 0, 0);
                c = __builtin_amdgcn_mfma_f32_16x16x32_bf16(fam[mt], fbm[nt], c, 0, 0, 0);
                acc[mt][nt] = c;
            }
    }

    // epilogue: C/D layout col=lane&15, row=quad*4+reg
#pragma unroll
    for (int mt = 0; mt < 4; mt++) {
        const int row0 = m0 + wm * 64 + mt * 16 + q * 4;
#pragma unroll
        for (int nt = 0; nt < 4; nt++) {
            const int col = n0 + wn * 64 + nt * 16 + l16;
#pragma unroll
            for (int r = 0; r < 4; r++)
                C[(size_t)(row0 + r) * N + col] = acc[mt][nt][r];
        }
    }
}

// ---------------------------------------------------------------------------
// Attention part. qkv layout: [b*S+s][3072], q at h*64+d, k at +1024, v at +2048
// ---------------------------------------------------------------------------

__global__ __launch_bounds__(256) void k_sums(const float* __restrict__ qkv,
                                              float* __restrict__ SQB,
                                              float* __restrict__ SK)
{
    const int lane = threadIdx.x & 63;
    const int pos  = blockIdx.x * 4 + (threadIdx.x >> 6);
    const int bh = pos >> 10, s = pos & 1023;
    const int b = bh >> 4, h = bh & 15;
    const float* base = qkv + (size_t)(b * SEQ + s) * E3D + h * DHEAD + lane;
    float xq = clampx(base[0]);
    float xk = clampx(base[1024]);
    float Tq[6], Tk[6];
    cheb5(xq, Tq); cheb5(xk, Tk);
    const float BETA[5] = {BETA1, BETA2, BETA3, BETA4, BETA5};
#pragma unroll
    for (int p = 1; p <= 5; p++) {
        float sq = wave_sum(Tq[p]);
        float sk = wave_sum(Tk[p]);
        if (lane == 0) {
            SQB[(size_t)pos * 5 + p - 1] = sq * BETA[p - 1];
            SK[(size_t)pos * 5 + p - 1]  = sk;
        }
    }
}

__global__ __launch_bounds__(128) void k_denprefix(const float* __restrict__ SK,
                                                   float* __restrict__ SKP)
{
    __shared__ float sums[NCHUNK][5];
    const int bh = blockIdx.x;
    const int t = threadIdx.x;
    if (t < NCHUNK * 5) {
        const int chunk = t / 5, p = t % 5;
        float s = 0.f;
        const float* base = SK + ((size_t)bh * SEQ + chunk * CHUNK) * 5 + p;
        for (int i = 0; i < CHUNK; i++) s += base[i * 5];
        sums[chunk][p] = s;
    }
    __syncthreads();
    if (t < 5) {
        float run = 0.f;
        for (int c = 0; c < NCHUNK; c++) {
            SKP[(size_t)(bh * NCHUNK + c) * 5 + t] = run;
            run += sums[c][t];
        }
    }
}

__global__ __launch_bounds__(64) void k_den(const float* __restrict__ SK,
                                            const float* __restrict__ SKP,
                                            const float* __restrict__ SQB,
                                            float* __restrict__ DEN)
{
    const int lane = threadIdx.x;
    const int blk = blockIdx.x;
    const int bh = blk >> 4, chunk = blk & 15;
    const int pos = bh * SEQ + chunk * CHUNK + lane;
    float den = 0.f;
#pragma unroll
    for (int p = 0; p < 5; p++) {
        float x = SK[(size_t)pos * 5 + p];
#pragma unroll
        for (int off = 1; off < 64; off <<= 1) {
            float n = __shfl_up(x, off, 64);
            if (lane >= off) x += n;
        }
        float ks = SKP[(size_t)blk * 5 + p] + x;
        den += SQB[(size_t)pos * 5 + p] * ks;
    }
    DEN[pos] = den;
}

__global__ __launch_bounds__(64) void k_kvchunk(const float* __restrict__ qkv,
                                                float* __restrict__ KVC)
{
    const int lane = threadIdx.x;
    const int blk = blockIdx.x;
    const int bh = blk >> 4, chunk = blk & 15;
    const int b = bh >> 4, h = bh & 15;
    const float* kb = qkv + (size_t)(b * SEQ + chunk * CHUNK) * E3D + 1024 + h * DHEAD + lane;
    float kv[5] = {0.f, 0.f, 0.f, 0.f, 0.f};
    for (int i = 0; i < CHUNK; i++) {
        const float* row = kb + (size_t)i * E3D;
        float xk = clampx(row[0]);
        float v = row[1024];
        float T[6]; cheb5(xk, T);
#pragma unroll
        for (int p = 1; p <= 5; p++) kv[p - 1] += T[p] * v;
    }
#pragma unroll
    for (int p = 0; p < 5; p++) KVC[((size_t)blk * 5 + p) * 64 + lane] = kv[p];
}

__global__ void k_kvprefix(float* __restrict__ KVC)
{
    const int id = blockIdx.x * 256 + threadIdx.x;
    if (id >= BATCH * NHEADS * 5 * 64) return;
    const int bh = id / 320, rem = id % 320;
    float run = 0.f;
    for (int c = 0; c < NCHUNK; c++) {
        size_t idx = (size_t)(bh * NCHUNK + c) * 320 + rem;
        float t = KVC[idx];
        KVC[idx] = run;
        run += t;
    }
}

// Final per-position output; writes 3-way bf16 split of out_h directly.
__global__ __launch_bounds__(64) void k_out(const float* __restrict__ qkv,
                                            const float* __restrict__ KVC,
                                            const float* __restrict__ DEN,
                                            unsigned short* __restrict__ OH,
                                            unsigned short* __restrict__ OM,
                                            unsigned short* __restrict__ OL)
{
    const int lane = threadIdx.x;
    const int blk = blockIdx.x;
    const int bh = blk >> 4, chunk = blk & 15;
    const int b = bh >> 4, h = bh & 15;
    const float BETA[5] = {BETA1, BETA2, BETA3, BETA4, BETA5};
    float kv[5];
#pragma unroll
    for (int p = 0; p < 5; p++) kv[p] = KVC[((size_t)blk * 5 + p) * 64 + lane];
    const float* qb = qkv + (size_t)(b * SEQ + chunk * CHUNK) * E3D + h * DHEAD + lane;
    size_t obase = (size_t)(b * SEQ + chunk * CHUNK) * DMODEL + h * DHEAD + lane;
    for (int i = 0; i < CHUNK; i++) {
        const float* row = qb + (size_t)i * E3D;
        float xq = clampx(row[0]);
        float xk = clampx(row[1024]);
        float v = row[2048];
        float Tk_[6]; cheb5(xk, Tk_);
#pragma unroll
        for (int p = 1; p <= 5; p++) kv[p - 1] += Tk_[p] * v;
        float Tq_[6]; cheb5(xq, Tq_);
        float num = 0.f;
#pragma unroll
        for (int p = 1; p <= 5; p++) num += BETA[p - 1] * Tq_[p] * kv[p - 1];
        float den = DEN[(size_t)bh * SEQ + chunk * CHUNK + i];
        float val = num / (den + 1e-7f);
        unsigned short a = f2bf(val); float r1 = val - bf2f(a);
        unsigned short c = f2bf(r1);  float r2 = r1 - bf2f(c);
        size_t oi = obase + (size_t)i * DMODEL;
        OH[oi] = a; OM[oi] = c; OL[oi] = f2bf(r2);
    }
}

// ---------------------------------------------------------------------------

extern "C" void kernel_launch(void* const* d_in, const int* in_sizes, int n_in,
                              void* d_out, int out_size, void* d_ws, size_t ws_size,
                              hipStream_t stream)
{
    const float* x    = (const float*)d_in[0];  // (2,1024,1024)
    const float* Win  = (const float*)d_in[1];  // (3072,1024)
    const float* Wout = (const float*)d_in[2];  // (1024,1024)
    float* out = (float*)d_out;                 // (2,1024,1024)
    char* ws = (char*)d_ws;

    // workspace layout (byte offsets)
    float* QKV = (float*)(ws + 0);                              // 25,165,824 B
    unsigned short* Xh   = (unsigned short*)(ws + 25165824);    //  4,194,304
    unsigned short* Xm   = (unsigned short*)(ws + 29360128);
    unsigned short* Xl   = (unsigned short*)(ws + 33554432);
    // Win splits (dead after GEMM1) share this region with OUTH + Wout splits
    unsigned short* Winh = (unsigned short*)(ws + 37748736);    //  6,291,456 each
    unsigned short* Winm = (unsigned short*)(ws + 44040192);
    unsigned short* Winl = (unsigned short*)(ws + 50331648);
    unsigned short* OHh  = (unsigned short*)(ws + 37748736);    //  4,194,304 each
    unsigned short* OHm  = (unsigned short*)(ws + 41943040);
    unsigned short* OHl  = (unsigned short*)(ws + 46137344);
    unsigned short* Wouth = (unsigned short*)(ws + 50331648);   //  2,097,152 each
    unsigned short* Woutm = (unsigned short*)(ws + 52428800);
    unsigned short* Woutl = (unsigned short*)(ws + 54525952);
    float* SQB = (float*)(ws + 56623104);
    float* SK  = (float*)(ws + 57278464);
    float* SKP = (float*)(ws + 57933824);
    float* DEN = (float*)(ws + 57944064);
    float* KVC = (float*)(ws + 58075136);
    // total: 58,730,496 B

    // split inputs
    k_split3<<<2048, 256, 0, stream>>>(x,   Xh,   Xm,   Xl,   524288);
    k_split3<<<3072, 256, 0, stream>>>(Win, Winh, Winm, Winl, 786432);

    // 1) QKV projection (M=2048, N=3072, K=1024)
    gemm_split3<<<dim3(24, 16), 256, 0, stream>>>(Xh, Xm, Xl, Winh, Winm, Winl,
                                                  QKV, BATCH * SEQ, E3D, DMODEL);

    // 2) attention scans
    k_sums<<<8192, 256, 0, stream>>>(QKV, SQB, SK);
    k_denprefix<<<BATCH * NHEADS, 128, 0, stream>>>(SK, SKP);
    k_den<<<BATCH * NHEADS * NCHUNK, 64, 0, stream>>>(SK, SKP, SQB, DEN);
    k_kvchunk<<<BATCH * NHEADS * NCHUNK, 64, 0, stream>>>(QKV, KVC);
    k_kvprefix<<<40, 256, 0, stream>>>(KVC);
    k_out<<<BATCH * NHEADS * NCHUNK, 64, 0, stream>>>(QKV, KVC, DEN, OHh, OHm, OHl);

    // split W_out (after GEMM1 so it may overwrite Winl region)
    k_split3<<<1024, 256, 0, stream>>>(Wout, Wouth, Woutm, Woutl, 262144);

    // 3) output projection (M=2048, N=1024, K=1024)
    gemm_split3<<<dim3(8, 16), 256, 0, stream>>>(OHh, OHm, OHl, Wouth, Woutm, Woutl,
                                                 out, BATCH * SEQ, DMODEL, DMODEL);
}

// Round 3
// 228.664 us; speedup vs baseline: 1.8360x; 1.2059x over previous
//
#include <hip/hip_runtime.h>
#include <hip/hip_bf16.h>
#include <cstddef>
#include <cstdint>

// Problem constants
#define BATCH 2
#define SEQ   1024
#define DMODEL 1024
#define NHEADS 16
#define DHEAD 64
#define E3D   3072
#define NCHUNK 64   // chunks along S
#define CHUNK 16    // positions per chunk

// beta (normalized), nonzero only for p=1..5 (T1..T5)
#define BETA1 0.45736626f
#define BETA2 0.26218724f
#define BETA3 0.15594524f
#define BETA4 0.08693904f
#define BETA5 0.03756222f

typedef __attribute__((ext_vector_type(8))) short short8;
typedef __attribute__((ext_vector_type(4))) float floatx4;

__device__ __forceinline__ unsigned short f2bf(float f) {
    unsigned u = __float_as_uint(f);
    u += 0x7fffu + ((u >> 16) & 1u);   // round-to-nearest-even
    return (unsigned short)(u >> 16);
}
__device__ __forceinline__ float bf2f(unsigned short h) {
    return __uint_as_float(((unsigned)h) << 16);
}

__device__ __forceinline__ void cp16(const void* g, void* l) {
    __builtin_amdgcn_global_load_lds(
        (const __attribute__((address_space(1))) void*)(uintptr_t)g,
        (__attribute__((address_space(3))) void*)(uintptr_t)l,
        16, 0, 0);
}

__device__ __forceinline__ void cheb5(float x, float T[6]) {
    T[0] = 1.f; T[1] = x;
    float tx2 = 2.f * x;
    T[2] = tx2 * T[1] - T[0];
    T[3] = tx2 * T[2] - T[1];
    T[4] = tx2 * T[3] - T[2];
    T[5] = tx2 * T[4] - T[3];
}

__device__ __forceinline__ float clampx(float v) {
    return fminf(fmaxf(v * 0.125f, -1.f + 1e-6f), 1.f - 1e-6f);
}

__device__ __forceinline__ float wave_sum(float x) {
#pragma unroll
    for (int m = 32; m >= 1; m >>= 1) x += __shfl_xor(x, m, 64);
    return x;
}

__device__ __forceinline__ void split3w(float v, unsigned short* H,
                                        unsigned short* M, unsigned short* L) {
    unsigned short a = f2bf(v); float r1 = v - bf2f(a);
    unsigned short b = f2bf(r1); float r2 = r1 - bf2f(b);
    *H = a; *M = b; *L = f2bf(r2);
}

// ---------------------------------------------------------------------------
// Split fp32 -> 3x bf16 (hi, mid, lo). Generic single-tensor version (Wout).
// ---------------------------------------------------------------------------
__global__ __launch_bounds__(256) void k_split3(const float* __restrict__ in,
                                                unsigned short* __restrict__ h,
                                                unsigned short* __restrict__ m,
                                                unsigned short* __restrict__ l,
                                                int n4)
{
    int i = blockIdx.x * 256 + threadIdx.x;
    if (i >= n4) return;
    float4 v = ((const float4*)in)[i];
    float vv[4] = {v.x, v.y, v.z, v.w};
    unsigned short hh[4], mm[4], ll[4];
#pragma unroll
    for (int j = 0; j < 4; j++) split3w(vv[j], &hh[j], &mm[j], &ll[j]);
    ((ushort4*)h)[i] = make_ushort4(hh[0], hh[1], hh[2], hh[3]);
    ((ushort4*)m)[i] = make_ushort4(mm[0], mm[1], mm[2], mm[3]);
    ((ushort4*)l)[i] = make_ushort4(ll[0], ll[1], ll[2], ll[3]);
}

// Fused split of x (2048 blocks worth) and Win (3072 blocks worth).
__global__ __launch_bounds__(256) void k_splitall(
    const float* __restrict__ x, const float* __restrict__ Win,
    unsigned short* __restrict__ Xh, unsigned short* __restrict__ Xm,
    unsigned short* __restrict__ Xl,
    unsigned short* __restrict__ Wh, unsigned short* __restrict__ Wm,
    unsigned short* __restrict__ Wl)
{
    const float* in; unsigned short *h, *m, *l; int i;
    if (blockIdx.x < 2048) {
        in = x; h = Xh; m = Xm; l = Xl;
        i = blockIdx.x * 256 + threadIdx.x;
    } else {
        in = Win; h = Wh; m = Wm; l = Wl;
        i = (blockIdx.x - 2048) * 256 + threadIdx.x;
    }
    float4 v = ((const float4*)in)[i];
    float vv[4] = {v.x, v.y, v.z, v.w};
    unsigned short hh[4], mm[4], ll[4];
#pragma unroll
    for (int j = 0; j < 4; j++) split3w(vv[j], &hh[j], &mm[j], &ll[j]);
    ((ushort4*)h)[i] = make_ushort4(hh[0], hh[1], hh[2], hh[3]);
    ((ushort4*)m)[i] = make_ushort4(mm[0], mm[1], mm[2], mm[3]);
    ((ushort4*)l)[i] = make_ushort4(ll[0], ll[1], ll[2], ll[3]);
}

// ---------------------------------------------------------------------------
// Split-bf16 MFMA GEMM: C[m,n] = sum_k A[m,k]*B[n,k], 3-way bf16 splits,
// K-major. Block tile TM x 128, BK=32, 256 threads = 4 waves (2x2), each wave
// (TM/32)x4 grid of 16x16x32 MFMA tiles. global_load_lds staging with XOR
// segment swizzle s = p ^ ((r>>1)&3) -> conflict-free ds_read_b128 frags.
// ---------------------------------------------------------------------------
template<int TM>
__global__ __launch_bounds__(256) void gemm_split3(
    const unsigned short* __restrict__ Ah, const unsigned short* __restrict__ Am,
    const unsigned short* __restrict__ Al,
    const unsigned short* __restrict__ Bh, const unsigned short* __restrict__ Bm,
    const unsigned short* __restrict__ Bl,
    float* __restrict__ C, int M, int N, int K)
{
    constexpr int ASZ = TM * 32;       // shorts per A split tile
    constexpr int BSZ = 128 * 32;      // shorts per B split tile
    constexpr int MT  = TM / 32;       // m-tiles per wave
    __shared__ unsigned short lds[3 * ASZ + 3 * BSZ];

    const int tid  = threadIdx.x;
    const int w    = tid >> 6;
    const int lane = tid & 63;
    const int m0 = blockIdx.y * TM;
    const int n0 = blockIdx.x * 128;

    // staging: each lane covers tile-row r, seg-position p=(lane&3);
    // fetch global segment s = p ^ ((r>>1)&3)
    const int rA0 = w * (TM / 4) + (lane >> 2);
    const int sA0 = (lane & 3) ^ ((rA0 >> 1) & 3);
    const size_t offA0 = (size_t)(m0 + rA0) * K + sA0 * 8;
    const int rA1 = rA0 + 16;
    const int sA1 = (lane & 3) ^ ((rA1 >> 1) & 3);
    const size_t offA1 = (size_t)(m0 + rA1) * K + sA1 * 8;
    const int ldsA0 = (w * (TM / 4)) * 32;
    const int ldsA1 = (w * (TM / 4) + 16) * 32;

    const int rB0 = w * 32 + (lane >> 2);
    const int rB1 = rB0 + 16;
    const int sB0 = (lane & 3) ^ ((rB0 >> 1) & 3);
    const int sB1 = (lane & 3) ^ ((rB1 >> 1) & 3);
    const size_t offB0 = (size_t)(n0 + rB0) * K + sB0 * 8;
    const size_t offB1 = (size_t)(n0 + rB1) * K + sB1 * 8;
    const int ldsB0 = (w * 32) * 32;
    const int ldsB1 = (w * 32 + 16) * 32;

    const unsigned short* gA[3] = {Ah, Am, Al};
    const unsigned short* gB[3] = {Bh, Bm, Bl};

    // fragment read addresses
    const int q = lane >> 4, l16 = lane & 15;
    const int wm = w & 1, wn = w >> 1;
    const int ra = wm * (TM / 2) + l16;
    const int rb = wn * 64 + l16;
    const int aadr = ra * 32 + ((q ^ ((ra >> 1) & 3)) * 8);
    const int badr = rb * 32 + ((q ^ ((rb >> 1) & 3)) * 8);

    floatx4 acc[MT][4] = {};

    for (int k0 = 0; k0 < K; k0 += 32) {
        __syncthreads();
#pragma unroll
        for (int b = 0; b < 3; b++) {
            cp16(gA[b] + offA0 + k0, &lds[b * ASZ + ldsA0]);
            if (TM == 128) cp16(gA[b] + offA1 + k0, &lds[b * ASZ + ldsA1]);
            cp16(gB[b] + offB0 + k0, &lds[3 * ASZ + b * BSZ + ldsB0]);
            cp16(gB[b] + offB1 + k0, &lds[3 * ASZ + b * BSZ + ldsB1]);
        }
        __syncthreads();

        short8 fah[MT], fam[MT], fal[MT], fbh[4], fbm[4], fbl[4];
#pragma unroll
        for (int t = 0; t < MT; t++) {
            fah[t] = *(const short8*)&lds[0 * ASZ + aadr + t * 512];
            fam[t] = *(const short8*)&lds[1 * ASZ + aadr + t * 512];
            fal[t] = *(const short8*)&lds[2 * ASZ + aadr + t * 512];
        }
#pragma unroll
        for (int t = 0; t < 4; t++) {
            fbh[t] = *(const short8*)&lds[3 * ASZ + 0 * BSZ + badr + t * 512];
            fbm[t] = *(const short8*)&lds[3 * ASZ + 1 * BSZ + badr + t * 512];
            fbl[t] = *(const short8*)&lds[3 * ASZ + 2 * BSZ + badr + t * 512];
        }
#pragma unroll
        for (int mt = 0; mt < MT; mt++)
#pragma unroll
            for (int nt = 0; nt < 4; nt++) {
                floatx4 c = acc[mt][nt];
                c = __builtin_amdgcn_mfma_f32_16x16x32_bf16(fah[mt], fbh[nt], c, 0, 0, 0);
                c = __builtin_amdgcn_mfma_f32_16x16x32_bf16(fah[mt], fbm[nt], c, 0, 0, 0);
                c = __builtin_amdgcn_mfma_f32_16x16x32_bf16(fam[mt], fbh[nt], c, 0, 0, 0);
                c = __builtin_amdgcn_mfma_f32_16x16x32_bf16(fah[mt], fbl[nt], c, 0, 0, 0);
                c = __builtin_amdgcn_mfma_f32_16x16x32_bf16(fal[mt], fbh[nt], c, 0, 0, 0);
                c = __builtin_amdgcn_mfma_f32_16x16x32_bf16(fam[mt], fbm[nt], c, 0, 0, 0);
                acc[mt][nt] = c;
            }
    }

    // epilogue: C/D layout col=lane&15, row=quad*4+reg
#pragma unroll
    for (int mt = 0; mt < MT; mt++) {
        const int row0 = m0 + wm * (TM / 2) + mt * 16 + q * 4;
#pragma unroll
        for (int nt = 0; nt < 4; nt++) {
            const int col = n0 + wn * 64 + nt * 16 + l16;
#pragma unroll
            for (int r = 0; r < 4; r++)
                C[(size_t)(row0 + r) * N + col] = acc[mt][nt][r];
        }
    }
}

// ---------------------------------------------------------------------------
// Attention. qkv layout: [b*S+s][3072], q at h*64+d, k at +1024, v at +2048
// ---------------------------------------------------------------------------

// Per-position head-sums: SQB[pos,p] = beta_p * sum_d Tq[p,d], SK[pos,p] = sum_d Tk[p,d]
__global__ __launch_bounds__(256) void k_sums(const float* __restrict__ qkv,
                                              float* __restrict__ SQB,
                                              float* __restrict__ SK)
{
    const int lane = threadIdx.x & 63;
    const int pos  = blockIdx.x * 4 + (threadIdx.x >> 6);
    const int bh = pos >> 10, s = pos & 1023;
    const int b = bh >> 4, h = bh & 15;
    const float* base = qkv + (size_t)(b * SEQ + s) * E3D + h * DHEAD + lane;
    float xq = clampx(base[0]);
    float xk = clampx(base[1024]);
    float Tq[6], Tk[6];
    cheb5(xq, Tq); cheb5(xk, Tk);
    const float BETA[5] = {BETA1, BETA2, BETA3, BETA4, BETA5};
#pragma unroll
    for (int p = 1; p <= 5; p++) {
        float sq = wave_sum(Tq[p]);
        float sk = wave_sum(Tk[p]);
        if (lane == 0) {
            SQB[(size_t)pos * 5 + p - 1] = sq * BETA[p - 1];
            SK[(size_t)pos * 5 + p - 1]  = sk;
        }
    }
}

// Chunk totals of kv. One wave per chunk (4 waves/block). cid = bh*64+chunk.
__global__ __launch_bounds__(256) void k_kvchunk(const float* __restrict__ qkv,
                                                 float* __restrict__ KVC)
{
    const int lane = threadIdx.x & 63;
    const int cid = blockIdx.x * 4 + (threadIdx.x >> 6);
    const int bh = cid >> 6, chunk = cid & 63;
    const int b = bh >> 4, h = bh & 15;
    const float* kb = qkv + (size_t)(b * SEQ + chunk * CHUNK) * E3D + 1024 + h * DHEAD + lane;
    float kv[5] = {0.f, 0.f, 0.f, 0.f, 0.f};
#pragma unroll
    for (int i = 0; i < CHUNK; i++) {
        const float* row = kb + (size_t)i * E3D;
        float xk = clampx(row[0]);
        float v = row[1024];
        float T[6]; cheb5(xk, T);
#pragma unroll
        for (int p = 1; p <= 5; p++) kv[p - 1] += T[p] * v;
    }
#pragma unroll
    for (int p = 0; p < 5; p++) KVC[((size_t)cid * 5 + p) * 64 + lane] = kv[p];
}

// Fused: (A) exclusive prefix over chunks of KVC in place; (B) SK chunk sums
// + exclusive prefix -> SKP. One block per bh, 320 threads.
__global__ __launch_bounds__(320) void k_prefix(float* __restrict__ KVC,
                                                const float* __restrict__ SK,
                                                float* __restrict__ SKP)
{
    __shared__ float csum[NCHUNK * 5];
    const int bh = blockIdx.x;
    const int t = threadIdx.x;   // 0..319
    // A: kv exclusive prefix, component t = p*64+d
    {
        float run = 0.f;
        size_t base = (size_t)bh * NCHUNK * 320 + t;
        for (int c = 0; c < NCHUNK; c++) {
            size_t idx = base + (size_t)c * 320;
            float v = KVC[idx];
            KVC[idx] = run;
            run += v;
        }
    }
    // B: SK chunk sums, (chunk, p) = (t/5, t%5)
    {
        const int chunk = t / 5, p = t % 5;
        const float* sb = SK + ((size_t)bh * SEQ + chunk * CHUNK) * 5 + p;
        float s = 0.f;
#pragma unroll
        for (int i = 0; i < CHUNK; i++) s += sb[i * 5];
        csum[chunk * 5 + p] = s;
    }
    __syncthreads();
    if (t < 5) {
        float run = 0.f;
        for (int c = 0; c < NCHUNK; c++) {
            SKP[((size_t)bh * NCHUNK + c) * 5 + t] = run;
            run += csum[c * 5 + t];
        }
    }
}

// Fused den + output. One wave per chunk (4 waves/block). Lane = d.
// den for position i computed by lane i (16-lane prefix), broadcast via shfl.
__global__ __launch_bounds__(256) void k_out(const float* __restrict__ qkv,
                                             const float* __restrict__ KVC,
                                             const float* __restrict__ SK,
                                             const float* __restrict__ SKP,
                                             const float* __restrict__ SQB,
                                             unsigned short* __restrict__ OH,
                                             unsigned short* __restrict__ OM,
                                             unsigned short* __restrict__ OL)
{
    const int lane = threadIdx.x & 63;
    const int cid = blockIdx.x * 4 + (threadIdx.x >> 6);
    const int bh = cid >> 6, chunk = cid & 63;
    const int b = bh >> 4, h = bh & 15;
    const float BETA[5] = {BETA1, BETA2, BETA3, BETA4, BETA5};

    // den phase: each 16-lane group computes all 16 positions (groups redundant)
    const int li = lane & 15;
    const int pos = bh * SEQ + chunk * CHUNK + li;
    float den_r = 0.f;
#pragma unroll
    for (int p = 0; p < 5; p++) {
        float v = SK[(size_t)pos * 5 + p];
#pragma unroll
        for (int off = 1; off < 16; off <<= 1) {
            float n = __shfl_up(v, off, 64);
            if (li >= off) v += n;
        }
        den_r += SQB[(size_t)pos * 5 + p] * (SKP[((size_t)bh * NCHUNK + chunk) * 5 + p] + v);
    }

    float kv[5];
#pragma unroll
    for (int p = 0; p < 5; p++) kv[p] = KVC[((size_t)cid * 5 + p) * 64 + lane];

    const float* qb = qkv + (size_t)(b * SEQ + chunk * CHUNK) * E3D + h * DHEAD + lane;
    size_t obase = (size_t)(b * SEQ + chunk * CHUNK) * DMODEL + h * DHEAD + lane;
#pragma unroll
    for (int i = 0; i < CHUNK; i++) {
        const float* row = qb + (size_t)i * E3D;
        float xq = clampx(row[0]);
        float xk = clampx(row[1024]);
        float v = row[2048];
        float Tk_[6]; cheb5(xk, Tk_);
#pragma unroll
        for (int p = 1; p <= 5; p++) kv[p - 1] += Tk_[p] * v;
        float Tq_[6]; cheb5(xq, Tq_);
        float num = 0.f;
#pragma unroll
        for (int p = 1; p <= 5; p++) num += BETA[p - 1] * Tq_[p] * kv[p - 1];
        float d = __shfl(den_r, i, 64);
        float val = num / (d + 1e-7f);
        unsigned short hh, mm, ll;
        split3w(val, &hh, &mm, &ll);
        size_t oi = obase + (size_t)i * DMODEL;
        OH[oi] = hh; OM[oi] = mm; OL[oi] = ll;
    }
}

// ---------------------------------------------------------------------------

extern "C" void kernel_launch(void* const* d_in, const int* in_sizes, int n_in,
                              void* d_out, int out_size, void* d_ws, size_t ws_size,
                              hipStream_t stream)
{
    const float* x    = (const float*)d_in[0];  // (2,1024,1024)
    const float* Win  = (const float*)d_in[1];  // (3072,1024)
    const float* Wout = (const float*)d_in[2];  // (1024,1024)
    float* out = (float*)d_out;                 // (2,1024,1024)
    char* ws = (char*)d_ws;

    // workspace layout (byte offsets)
    float* QKV = (float*)(ws + 0);                              // 25,165,824 B
    unsigned short* Xh   = (unsigned short*)(ws + 25165824);    //  4,194,304 each
    unsigned short* Xm   = (unsigned short*)(ws + 29360128);
    unsigned short* Xl   = (unsigned short*)(ws + 33554432);
    unsigned short* Winh = (unsigned short*)(ws + 37748736);    //  6,291,456 each
    unsigned short* Winm = (unsigned short*)(ws + 44040192);
    unsigned short* Winl = (unsigned short*)(ws + 50331648);
    // After GEMM1, Win splits die -> OH splits + Wout splits reuse the region
    unsigned short* OHh  = (unsigned short*)(ws + 37748736);    //  4,194,304 each
    unsigned short* OHm  = (unsigned short*)(ws + 41943040);
    unsigned short* OHl  = (unsigned short*)(ws + 46137344);
    unsigned short* Wouth = (unsigned short*)(ws + 50331648);   //  2,097,152 each
    unsigned short* Woutm = (unsigned short*)(ws + 52428800);
    unsigned short* Woutl = (unsigned short*)(ws + 54525952);
    // After GEMM1, X splits die too -> attention scratch reuses that region
    float* SQB = (float*)(ws + 25165824);   // 655,360 B
    float* SK  = (float*)(ws + 25821184);   // 655,360 B
    float* SKP = (float*)(ws + 26476544);   //  40,960 B
    float* KVC = (float*)(ws + 26517504);   // 2,621,440 B (end 29,138,944)
    // max ws use: 56,623,104 B (< round-2's proven 58.7 MB)

    // split x + Win (one launch)
    k_splitall<<<5120, 256, 0, stream>>>(x, Win, Xh, Xm, Xl, Winh, Winm, Winl);

    // 1) QKV projection (M=2048, N=3072, K=1024)
    gemm_split3<128><<<dim3(24, 16), 256, 0, stream>>>(Xh, Xm, Xl, Winh, Winm, Winl,
                                                       QKV, BATCH * SEQ, E3D, DMODEL);

    // split W_out (X/Win regions now dead)
    k_split3<<<1024, 256, 0, stream>>>(Wout, Wouth, Woutm, Woutl, 262144);

    // 2) attention
    k_sums<<<8192, 256, 0, stream>>>(QKV, SQB, SK);
    k_kvchunk<<<512, 256, 0, stream>>>(QKV, KVC);
    k_prefix<<<BATCH * NHEADS, 320, 0, stream>>>(KVC, SK, SKP);
    k_out<<<512, 256, 0, stream>>>(QKV, KVC, SK, SKP, SQB, OHh, OHm, OHl);

    // 3) output projection (M=2048, N=1024, K=1024), 64x128 tiles -> 256 blocks
    gemm_split3<64><<<dim3(8, 32), 256, 0, stream>>>(OHh, OHm, OHl, Wouth, Woutm, Woutl,
                                                     out, BATCH * SEQ, DMODEL, DMODEL);
}

// Round 4
// 181.120 us; speedup vs baseline: 2.3180x; 1.2625x over previous
//
#include <hip/hip_runtime.h>
#include <hip/hip_bf16.h>
#include <cstddef>
#include <cstdint>

// Problem constants
#define BATCH 2
#define SEQ   1024
#define DMODEL 1024
#define NHEADS 16
#define DHEAD 64
#define E3D   3072
#define NCHUNK 64   // chunks along S
#define CHUNK 16    // positions per chunk

// beta (normalized), nonzero only for p=1..5 (T1..T5)
#define BETA1 0.45736626f
#define BETA2 0.26218724f
#define BETA3 0.15594524f
#define BETA4 0.08693904f
#define BETA5 0.03756222f

#define RSCALE 2048.f
#define RINV   4.8828125e-4f   // 1/2048

typedef __attribute__((ext_vector_type(8))) _Float16 half8;
typedef __attribute__((ext_vector_type(4))) float floatx4;

__device__ __forceinline__ void cp16(const void* g, void* l) {
    __builtin_amdgcn_global_load_lds(
        (const __attribute__((address_space(1))) void*)(uintptr_t)g,
        (__attribute__((address_space(3))) void*)(uintptr_t)l,
        16, 0, 0);
}

// fp16 2-level split: x ~= h + m/2048 (residual pre-scaled so it stays normal)
__device__ __forceinline__ void split2(float x, unsigned short* H, unsigned short* M) {
    _Float16 h = (_Float16)x;
    float r = (x - (float)h) * RSCALE;
    _Float16 m = (_Float16)r;
    *H = __builtin_bit_cast(unsigned short, h);
    *M = __builtin_bit_cast(unsigned short, m);
}

__device__ __forceinline__ void split2x4(const float4 v,
                                         unsigned short* h, unsigned short* m,
                                         size_t i4) {
    float vv[4] = {v.x, v.y, v.z, v.w};
    unsigned short hh[4], mm[4];
#pragma unroll
    for (int j = 0; j < 4; j++) split2(vv[j], &hh[j], &mm[j]);
    ((ushort4*)h)[i4] = make_ushort4(hh[0], hh[1], hh[2], hh[3]);
    ((ushort4*)m)[i4] = make_ushort4(mm[0], mm[1], mm[2], mm[3]);
}

__device__ __forceinline__ void cheb5(float x, float T[6]) {
    T[0] = 1.f; T[1] = x;
    float tx2 = 2.f * x;
    T[2] = tx2 * T[1] - T[0];
    T[3] = tx2 * T[2] - T[1];
    T[4] = tx2 * T[3] - T[2];
    T[5] = tx2 * T[4] - T[3];
}

__device__ __forceinline__ float clampx(float v) {
    return fminf(fmaxf(v * 0.125f, -1.f + 1e-6f), 1.f - 1e-6f);
}

__device__ __forceinline__ float wave_sum(float x) {
#pragma unroll
    for (int m = 32; m >= 1; m >>= 1) x += __shfl_xor(x, m, 64);
    return x;
}

// ---------------------------------------------------------------------------
// Fused split of x (2048 blocks) and Win (3072 blocks): fp16 2-level.
// ---------------------------------------------------------------------------
__global__ __launch_bounds__(256) void k_splitall(
    const float* __restrict__ x, const float* __restrict__ Win,
    unsigned short* __restrict__ Xh, unsigned short* __restrict__ Xm,
    unsigned short* __restrict__ Wh, unsigned short* __restrict__ Wm)
{
    const float* in; unsigned short *h, *m; int i;
    if (blockIdx.x < 2048) {
        in = x; h = Xh; m = Xm;
        i = blockIdx.x * 256 + threadIdx.x;
    } else {
        in = Win; h = Wh; m = Wm;
        i = (blockIdx.x - 2048) * 256 + threadIdx.x;
    }
    split2x4(((const float4*)in)[i], h, m, i);
}

// ---------------------------------------------------------------------------
// fp16 scaled-residual MFMA GEMM: C[m,n] = sum_k A[m,k]*B[n,k].
// A = Ah + Am/2048, B likewise. 3 MFMAs per tile:
//   acc1 += Ah*Bh ; acc2 += Ah*Bm + Am*Bh ; C = acc1 + acc2/2048.
// Block tile TM x 128, BK=32, 256 threads = 4 waves (2x2), each wave
// (TM/32 if >=64 else 1) x 4 grid of 16x16x32 f16 MFMA tiles.
// global_load_lds staging with XOR segment swizzle s = p ^ ((r>>1)&3)
// (lane's global source is swizzled; LDS dest is linear lane*16B) ->
// conflict-free ds_read_b128 fragment reads (verified 0 conflicts R2/R3).
// ---------------------------------------------------------------------------
template<int TM>
__global__ __launch_bounds__(256, 3) void gemm_f16s(
    const unsigned short* __restrict__ Ah, const unsigned short* __restrict__ Am,
    const unsigned short* __restrict__ Bh, const unsigned short* __restrict__ Bm,
    float* __restrict__ C, int M, int N, int K)
{
    constexpr int ASZ = TM * 32;       // shorts per A split tile
    constexpr int BSZ = 128 * 32;      // shorts per B split tile
    constexpr int MT  = (TM >= 64) ? TM / 32 : 1;   // m-tiles per wave
    __shared__ unsigned short lds[2 * ASZ + 2 * BSZ];

    const int tid  = threadIdx.x;
    const int w    = tid >> 6;
    const int lane = tid & 63;
    const int m0 = blockIdx.y * TM;
    const int n0 = blockIdx.x * 128;

    // ---- staging addresses (lane covers tile-row r, seg p=lane&3; global
    //      segment s = p ^ ((r>>1)&3); LDS dest = wave-uniform + lane*16B) ----
    // B: 128 rows, every wave stages rows w*32..w*32+31 (two cp16 per split)
    const int rB0 = w * 32 + (lane >> 2);
    const int rB1 = rB0 + 16;
    const int sB0 = (lane & 3) ^ ((rB0 >> 1) & 3);
    const int sB1 = (lane & 3) ^ ((rB1 >> 1) & 3);
    const size_t offB0 = (size_t)(n0 + rB0) * K + sB0 * 8;
    const size_t offB1 = (size_t)(n0 + rB1) * K + sB1 * 8;
    const int ldsB0 = (w * 32) * 32;
    const int ldsB1 = (w * 32 + 16) * 32;

    // A: TM rows. TM=64: all 4 waves stage 16 rows each. TM=32: waves 0,1 only.
    const int rA0 = (TM >= 64) ? (w * (TM / 4) + (lane >> 2))
                               : (w * 16 + (lane >> 2));
    const int sA0 = (lane & 3) ^ ((rA0 >> 1) & 3);
    const size_t offA0 = (size_t)(m0 + rA0) * K + sA0 * 8;
    const int ldsA0 = ((TM >= 64) ? (w * (TM / 4)) : (w * 16)) * 32;
    const bool doA = (TM >= 64) || (w < 2);

    // ---- fragment read addresses ----
    const int q = lane >> 4, l16 = lane & 15;
    const int wm = w & 1, wn = w >> 1;
    const int ra = wm * (TM / 2) + l16;
    const int rb = wn * 64 + l16;
    const int aadr = ra * 32 + ((q ^ ((ra >> 1) & 3)) * 8);
    const int badr = rb * 32 + ((q ^ ((rb >> 1) & 3)) * 8);

    floatx4 acc1[MT][4] = {};
    floatx4 acc2[MT][4] = {};

    for (int k0 = 0; k0 < K; k0 += 32) {
        __syncthreads();
        if (doA) {
            cp16(Ah + offA0 + k0, &lds[0 * ASZ + ldsA0]);
            cp16(Am + offA0 + k0, &lds[1 * ASZ + ldsA0]);
        }
        cp16(Bh + offB0 + k0, &lds[2 * ASZ + 0 * BSZ + ldsB0]);
        cp16(Bh + offB1 + k0, &lds[2 * ASZ + 0 * BSZ + ldsB1]);
        cp16(Bm + offB0 + k0, &lds[2 * ASZ + 1 * BSZ + ldsB0]);
        cp16(Bm + offB1 + k0, &lds[2 * ASZ + 1 * BSZ + ldsB1]);
        __syncthreads();

        half8 fah[MT], fam[MT], fbh[4], fbm[4];
#pragma unroll
        for (int t = 0; t < MT; t++) {
            fah[t] = *(const half8*)&lds[0 * ASZ + aadr + t * 512];
            fam[t] = *(const half8*)&lds[1 * ASZ + aadr + t * 512];
        }
#pragma unroll
        for (int t = 0; t < 4; t++) {
            fbh[t] = *(const half8*)&lds[2 * ASZ + 0 * BSZ + badr + t * 512];
            fbm[t] = *(const half8*)&lds[2 * ASZ + 1 * BSZ + badr + t * 512];
        }
#pragma unroll
        for (int mt = 0; mt < MT; mt++)
#pragma unroll
            for (int nt = 0; nt < 4; nt++) {
                acc1[mt][nt] = __builtin_amdgcn_mfma_f32_16x16x32_f16(
                    fah[mt], fbh[nt], acc1[mt][nt], 0, 0, 0);
                acc2[mt][nt] = __builtin_amdgcn_mfma_f32_16x16x32_f16(
                    fah[mt], fbm[nt], acc2[mt][nt], 0, 0, 0);
                acc2[mt][nt] = __builtin_amdgcn_mfma_f32_16x16x32_f16(
                    fam[mt], fbh[nt], acc2[mt][nt], 0, 0, 0);
            }
    }

    // epilogue: C/D layout col=lane&15, row=quad*4+reg
#pragma unroll
    for (int mt = 0; mt < MT; mt++) {
        const int row0 = m0 + wm * (TM / 2) + mt * 16 + q * 4;
#pragma unroll
        for (int nt = 0; nt < 4; nt++) {
            const int col = n0 + wn * 64 + nt * 16 + l16;
#pragma unroll
            for (int r = 0; r < 4; r++)
                C[(size_t)(row0 + r) * N + col] = acc1[mt][nt][r] + acc2[mt][nt][r] * RINV;
        }
    }
}

// ---------------------------------------------------------------------------
// Attention. qkv layout: [b*S+s][3072], q at h*64+d, k at +1024, v at +2048
// Fused mid kernel: [0,1024) Wout split | [1024,9216) per-position sums |
// [9216,9728) kv chunk totals.
// ---------------------------------------------------------------------------
__global__ __launch_bounds__(256) void k_mid(
    const float* __restrict__ Wout,
    unsigned short* __restrict__ Wouth, unsigned short* __restrict__ Woutm,
    const float* __restrict__ qkv,
    float* __restrict__ SQB, float* __restrict__ SK, float* __restrict__ KVC)
{
    const int blk = blockIdx.x;
    if (blk < 1024) {
        // Wout fp16 2-level split
        int i = blk * 256 + threadIdx.x;
        split2x4(((const float4*)Wout)[i], Wouth, Woutm, i);
        return;
    }
    if (blk < 9216) {
        // per-position head-sums: SQB[pos,p] = beta_p * sum_d Tq, SK = sum_d Tk
        const int lane = threadIdx.x & 63;
        const int pos  = (blk - 1024) * 4 + (threadIdx.x >> 6);
        const int bh = pos >> 10, s = pos & 1023;
        const int b = bh >> 4, h = bh & 15;
        const float* base = qkv + (size_t)(b * SEQ + s) * E3D + h * DHEAD + lane;
        float xq = clampx(base[0]);
        float xk = clampx(base[1024]);
        float Tq[6], Tk[6];
        cheb5(xq, Tq); cheb5(xk, Tk);
        const float BETA[5] = {BETA1, BETA2, BETA3, BETA4, BETA5};
#pragma unroll
        for (int p = 1; p <= 5; p++) {
            float sq = wave_sum(Tq[p]);
            float sk = wave_sum(Tk[p]);
            if (lane == 0) {
                SQB[(size_t)pos * 5 + p - 1] = sq * BETA[p - 1];
                SK[(size_t)pos * 5 + p - 1]  = sk;
            }
        }
        return;
    }
    // kv chunk totals: one wave per chunk, lane = d
    {
        const int lane = threadIdx.x & 63;
        const int cid = (blk - 9216) * 4 + (threadIdx.x >> 6);
        const int bh = cid >> 6, chunk = cid & 63;
        const int b = bh >> 4, h = bh & 15;
        const float* kb = qkv + (size_t)(b * SEQ + chunk * CHUNK) * E3D + 1024 + h * DHEAD + lane;
        float kv[5] = {0.f, 0.f, 0.f, 0.f, 0.f};
#pragma unroll
        for (int i = 0; i < CHUNK; i++) {
            const float* row = kb + (size_t)i * E3D;
            float xk = clampx(row[0]);
            float v = row[1024];
            float T[6]; cheb5(xk, T);
#pragma unroll
            for (int p = 1; p <= 5; p++) kv[p - 1] += T[p] * v;
        }
#pragma unroll
        for (int p = 0; p < 5; p++) KVC[((size_t)cid * 5 + p) * 64 + lane] = kv[p];
    }
}

// Fused prefixes: (A) exclusive prefix over chunks of KVC in place (values
// preloaded into registers -> 64 independent loads, not a dependent chain);
// (B) SK chunk sums + exclusive prefix -> SKP. One block per bh, 320 threads.
__global__ __launch_bounds__(320) void k_prefix(float* __restrict__ KVC,
                                                const float* __restrict__ SK,
                                                float* __restrict__ SKP)
{
    __shared__ float csum[NCHUNK * 5];
    const int bh = blockIdx.x;
    const int t = threadIdx.x;   // 0..319, component = p*64+d
    float v[NCHUNK];
    const size_t base = (size_t)bh * NCHUNK * 320 + t;
#pragma unroll
    for (int c = 0; c < NCHUNK; c++) v[c] = KVC[base + (size_t)c * 320];
    float run = 0.f;
#pragma unroll
    for (int c = 0; c < NCHUNK; c++) {
        KVC[base + (size_t)c * 320] = run;
        run += v[c];
    }
    // B: SK chunk sums, (chunk, p) = (t/5, t%5)
    {
        const int chunk = t / 5, p = t % 5;
        const float* sb = SK + ((size_t)bh * SEQ + chunk * CHUNK) * 5 + p;
        float s = 0.f;
#pragma unroll
        for (int i = 0; i < CHUNK; i++) s += sb[i * 5];
        csum[chunk * 5 + p] = s;
    }
    __syncthreads();
    if (t < 5) {
        float run2 = 0.f;
        for (int c = 0; c < NCHUNK; c++) {
            SKP[((size_t)bh * NCHUNK + c) * 5 + t] = run2;
            run2 += csum[c * 5 + t];
        }
    }
}

// Fused den + output. One wave per chunk (4 waves/block). Lane = d.
// Writes out_h directly as fp16 2-level split (GEMM2 A operand).
__global__ __launch_bounds__(256) void k_out(const float* __restrict__ qkv,
                                             const float* __restrict__ KVC,
                                             const float* __restrict__ SK,
                                             const float* __restrict__ SKP,
                                             const float* __restrict__ SQB,
                                             unsigned short* __restrict__ OH,
                                             unsigned short* __restrict__ OM)
{
    const int lane = threadIdx.x & 63;
    const int cid = blockIdx.x * 4 + (threadIdx.x >> 6);
    const int bh = cid >> 6, chunk = cid & 63;
    const int b = bh >> 4, h = bh & 15;
    const float BETA[5] = {BETA1, BETA2, BETA3, BETA4, BETA5};

    // den phase: each 16-lane group computes all 16 positions (groups redundant)
    const int li = lane & 15;
    const int pos = bh * SEQ + chunk * CHUNK + li;
    float den_r = 0.f;
#pragma unroll
    for (int p = 0; p < 5; p++) {
        float v = SK[(size_t)pos * 5 + p];
#pragma unroll
        for (int off = 1; off < 16; off <<= 1) {
            float n = __shfl_up(v, off, 64);
            if (li >= off) v += n;
        }
        den_r += SQB[(size_t)pos * 5 + p] * (SKP[((size_t)bh * NCHUNK + chunk) * 5 + p] + v);
    }

    float kv[5];
#pragma unroll
    for (int p = 0; p < 5; p++) kv[p] = KVC[((size_t)cid * 5 + p) * 64 + lane];

    const float* qb = qkv + (size_t)(b * SEQ + chunk * CHUNK) * E3D + h * DHEAD + lane;
    size_t obase = (size_t)(b * SEQ + chunk * CHUNK) * DMODEL + h * DHEAD + lane;
#pragma unroll
    for (int i = 0; i < CHUNK; i++) {
        const float* row = qb + (size_t)i * E3D;
        float xq = clampx(row[0]);
        float xk = clampx(row[1024]);
        float v = row[2048];
        float Tk_[6]; cheb5(xk, Tk_);
#pragma unroll
        for (int p = 1; p <= 5; p++) kv[p - 1] += Tk_[p] * v;
        float Tq_[6]; cheb5(xq, Tq_);
        float num = 0.f;
#pragma unroll
        for (int p = 1; p <= 5; p++) num += BETA[p - 1] * Tq_[p] * kv[p - 1];
        float d = __shfl(den_r, i, 64);
        float val = num / (d + 1e-7f);
        unsigned short hh, mm;
        split2(val, &hh, &mm);
        size_t oi = obase + (size_t)i * DMODEL;
        OH[oi] = hh; OM[oi] = mm;
    }
}

// ---------------------------------------------------------------------------

extern "C" void kernel_launch(void* const* d_in, const int* in_sizes, int n_in,
                              void* d_out, int out_size, void* d_ws, size_t ws_size,
                              hipStream_t stream)
{
    const float* x    = (const float*)d_in[0];  // (2,1024,1024)
    const float* Win  = (const float*)d_in[1];  // (3072,1024)
    const float* Wout = (const float*)d_in[2];  // (1024,1024)
    float* out = (float*)d_out;                 // (2,1024,1024)
    char* ws = (char*)d_ws;

    // workspace layout (byte offsets)
    float* QKV = (float*)(ws + 0);                              // 25,165,824 B
    unsigned short* Xh   = (unsigned short*)(ws + 25165824);    //  4,194,304 each
    unsigned short* Xm   = (unsigned short*)(ws + 29360128);
    unsigned short* Winh = (unsigned short*)(ws + 33554432);    //  6,291,456 each
    unsigned short* Winm = (unsigned short*)(ws + 39845888);    // end 46,137,344
    // After GEMM1, X/Win splits die -> reuse regions:
    float* SQB = (float*)(ws + 25165824);   // 655,360
    float* SK  = (float*)(ws + 25821184);   // 655,360
    float* SKP = (float*)(ws + 26476544);   //  40,960
    float* KVC = (float*)(ws + 26517504);   // 2,621,440 (end 29,138,944)
    unsigned short* OHh   = (unsigned short*)(ws + 33554432);   // 4,194,304 each
    unsigned short* OHm   = (unsigned short*)(ws + 37748736);
    unsigned short* Wouth = (unsigned short*)(ws + 41943040);   // 2,097,152 each
    unsigned short* Woutm = (unsigned short*)(ws + 44040192);   // end 46,137,344

    // split x + Win (one launch)
    k_splitall<<<5120, 256, 0, stream>>>(x, Win, Xh, Xm, Winh, Winm);

    // 1) QKV projection (M=2048, N=3072, K=1024): 64x128 tiles -> 768 blocks (3/CU)
    gemm_f16s<64><<<dim3(24, 32), 256, 0, stream>>>(Xh, Xm, Winh, Winm,
                                                    QKV, BATCH * SEQ, E3D, DMODEL);

    // 2) Wout split + per-position sums + kv chunk totals (one launch)
    k_mid<<<9728, 256, 0, stream>>>(Wout, Wouth, Woutm, QKV, SQB, SK, KVC);

    // 3) prefixes
    k_prefix<<<BATCH * NHEADS, 320, 0, stream>>>(KVC, SK, SKP);

    // 4) den + output (writes out_h as fp16 split)
    k_out<<<512, 256, 0, stream>>>(QKV, KVC, SK, SKP, SQB, OHh, OHm);

    // 5) output projection (M=2048, N=1024, K=1024): 32x128 tiles -> 512 blocks (2/CU)
    gemm_f16s<32><<<dim3(8, 64), 256, 0, stream>>>(OHh, OHm, Wouth, Woutm,
                                                   out, BATCH * SEQ, DMODEL, DMODEL);
}

// Round 5
// 179.657 us; speedup vs baseline: 2.3368x; 1.0081x over previous
//
#include <hip/hip_runtime.h>
#include <hip/hip_bf16.h>
#include <cstddef>
#include <cstdint>

// Problem constants
#define BATCH 2
#define SEQ   1024
#define DMODEL 1024
#define NHEADS 16
#define DHEAD 64
#define E3D   3072
#define NCHUNK 64   // chunks along S
#define CHUNK 16    // positions per chunk

// beta (normalized), nonzero only for p=1..5 (T1..T5)
#define BETA1 0.45736626f
#define BETA2 0.26218724f
#define BETA3 0.15594524f
#define BETA4 0.08693904f
#define BETA5 0.03756222f

#define RSCALE 2048.f
#define RINV   4.8828125e-4f   // 1/2048

typedef __attribute__((ext_vector_type(8))) _Float16 half8;
typedef __attribute__((ext_vector_type(16))) float floatx16;

__device__ __forceinline__ void cp16(const void* g, void* l) {
    __builtin_amdgcn_global_load_lds(
        (const __attribute__((address_space(1))) void*)(uintptr_t)g,
        (__attribute__((address_space(3))) void*)(uintptr_t)l,
        16, 0, 0);
}

// fp16 2-level split: x ~= h + m/2048 (residual pre-scaled so it stays normal)
__device__ __forceinline__ void split2(float x, unsigned short* H, unsigned short* M) {
    _Float16 h = (_Float16)x;
    float r = (x - (float)h) * RSCALE;
    _Float16 m = (_Float16)r;
    *H = __builtin_bit_cast(unsigned short, h);
    *M = __builtin_bit_cast(unsigned short, m);
}

__device__ __forceinline__ void split2x4(const float4 v,
                                         unsigned short* h, unsigned short* m,
                                         size_t i4) {
    float vv[4] = {v.x, v.y, v.z, v.w};
    unsigned short hh[4], mm[4];
#pragma unroll
    for (int j = 0; j < 4; j++) split2(vv[j], &hh[j], &mm[j]);
    ((ushort4*)h)[i4] = make_ushort4(hh[0], hh[1], hh[2], hh[3]);
    ((ushort4*)m)[i4] = make_ushort4(mm[0], mm[1], mm[2], mm[3]);
}

__device__ __forceinline__ void cheb5(float x, float T[6]) {
    T[0] = 1.f; T[1] = x;
    float tx2 = 2.f * x;
    T[2] = tx2 * T[1] - T[0];
    T[3] = tx2 * T[2] - T[1];
    T[4] = tx2 * T[3] - T[2];
    T[5] = tx2 * T[4] - T[3];
}

__device__ __forceinline__ float clampx(float v) {
    return fminf(fmaxf(v * 0.125f, -1.f + 1e-6f), 1.f - 1e-6f);
}

__device__ __forceinline__ float wave_sum(float x) {
#pragma unroll
    for (int m = 32; m >= 1; m >>= 1) x += __shfl_xor(x, m, 64);
    return x;
}

// ---------------------------------------------------------------------------
// Fused split of x (2048 blocks) and Win (3072 blocks): fp16 2-level.
// ---------------------------------------------------------------------------
__global__ __launch_bounds__(256) void k_splitall(
    const float* __restrict__ x, const float* __restrict__ Win,
    unsigned short* __restrict__ Xh, unsigned short* __restrict__ Xm,
    unsigned short* __restrict__ Wh, unsigned short* __restrict__ Wm)
{
    const float* in; unsigned short *h, *m; int i;
    if (blockIdx.x < 2048) {
        in = x; h = Xh; m = Xm;
        i = blockIdx.x * 256 + threadIdx.x;
    } else {
        in = Win; h = Wh; m = Wm;
        i = (blockIdx.x - 2048) * 256 + threadIdx.x;
    }
    split2x4(((const float4*)in)[i], h, m, i);
}

// ---------------------------------------------------------------------------
// fp16 scaled-residual MFMA GEMM (32x32x16): C[m,n] = sum_k A[m,k]*B[n,k].
// A = Ah + Am/2048, B likewise: acc1 += Ah*Bh; acc2 += Ah*Bm + Am*Bh;
// C = acc1 + acc2/2048.
// Block tile 64 x TN, BK=32, 256 threads = 4 waves (2x2); wave = 32 rows x
// (TN/2) cols = NT=TN/64 tiles of 32x32. MFMA = v_mfma_f32_32x32x16_f16:
//   A frag: m=lane&31, k=(lane>>5)*8+j ; B frag: n=lane&31, same k
//   C/D:    col=lane&31, row=(reg&3)+8*(reg>>2)+4*(lane>>5)
// global_load_lds staging with XOR segment swizzle: LDS row r position p
// holds global k-segment p ^ ((r>>1)&3) -> conflict-free ds_read_b128.
// ---------------------------------------------------------------------------
template<int TN>
__global__ __launch_bounds__(256, 2) void gemm_w32(
    const unsigned short* __restrict__ Ah, const unsigned short* __restrict__ Am,
    const unsigned short* __restrict__ Bh, const unsigned short* __restrict__ Bm,
    float* __restrict__ C, int M, int N, int K)
{
    constexpr int NT  = TN / 64;       // 32x32 N-tiles per wave
    constexpr int ASZ = 64 * 32;       // shorts per A split tile
    constexpr int BSZ = TN * 32;       // shorts per B split tile
    __shared__ unsigned short lds[2 * ASZ + 2 * BSZ];

    const int tid  = threadIdx.x;
    const int w    = tid >> 6;
    const int lane = tid & 63;
    const int m0 = blockIdx.y * 64;
    const int n0 = blockIdx.x * TN;

    // ---- staging addresses ----
    // A: 64 rows, one pass/split; thread covers row w*16+(lane>>2), seg lane&3
    const int arow = w * 16 + (lane >> 2);
    const int asg  = (lane & 3) ^ ((arow >> 1) & 3);
    const size_t offA = (size_t)(m0 + arow) * K + asg * 8;
    const int ldsA = (w * 16) * 32;
    // B: TN rows, NT passes/split
    size_t offB[NT];
    int ldsB[NT];
#pragma unroll
    for (int j = 0; j < NT; j++) {
        const int brow = j * 64 + w * 16 + (lane >> 2);
        const int bsg  = (lane & 3) ^ ((brow >> 1) & 3);
        offB[j] = (size_t)(n0 + brow) * K + bsg * 8;
        ldsB[j] = (j * 64 + w * 16) * 32;
    }

    // ---- fragment read addresses ----
    const int l32 = lane & 31, q32 = lane >> 5;
    const int wm = w & 1, wn = w >> 1;
    const int ra = wm * 32 + l32;
    const int abase = ra * 32, aswz = (ra >> 1) & 3;
    int bbase[NT], bswz[NT];
#pragma unroll
    for (int nt = 0; nt < NT; nt++) {
        const int rb = wn * (TN / 2) + nt * 32 + l32;
        bbase[nt] = rb * 32;
        bswz[nt] = (rb >> 1) & 3;
    }

    floatx16 acc1[NT] = {};
    floatx16 acc2[NT] = {};

    for (int k0 = 0; k0 < K; k0 += 32) {
        __syncthreads();
        cp16(Ah + offA + k0, &lds[ldsA]);
        cp16(Am + offA + k0, &lds[ASZ + ldsA]);
#pragma unroll
        for (int j = 0; j < NT; j++) {
            cp16(Bh + offB[j] + k0, &lds[2 * ASZ + ldsB[j]]);
            cp16(Bm + offB[j] + k0, &lds[2 * ASZ + BSZ + ldsB[j]]);
        }
        __syncthreads();

#pragma unroll
        for (int kk = 0; kk < 2; kk++) {
            const int ksel = kk * 2 + q32;
            half8 fah = *(const half8*)&lds[abase + ((ksel ^ aswz) * 8)];
            half8 fam = *(const half8*)&lds[ASZ + abase + ((ksel ^ aswz) * 8)];
            half8 fbh[NT], fbm[NT];
#pragma unroll
            for (int nt = 0; nt < NT; nt++) {
                fbh[nt] = *(const half8*)&lds[2 * ASZ + bbase[nt] + ((ksel ^ bswz[nt]) * 8)];
                fbm[nt] = *(const half8*)&lds[2 * ASZ + BSZ + bbase[nt] + ((ksel ^ bswz[nt]) * 8)];
            }
#pragma unroll
            for (int nt = 0; nt < NT; nt++) {
                acc1[nt] = __builtin_amdgcn_mfma_f32_32x32x16_f16(fah, fbh[nt], acc1[nt], 0, 0, 0);
                acc2[nt] = __builtin_amdgcn_mfma_f32_32x32x16_f16(fah, fbm[nt], acc2[nt], 0, 0, 0);
                acc2[nt] = __builtin_amdgcn_mfma_f32_32x32x16_f16(fam, fbh[nt], acc2[nt], 0, 0, 0);
            }
        }
    }

    // epilogue: col=lane&31, row=(reg&3)+8*(reg>>2)+4*(lane>>5)
    const int r0 = m0 + wm * 32 + q32 * 4;
#pragma unroll
    for (int nt = 0; nt < NT; nt++) {
        const int c0 = n0 + wn * (TN / 2) + nt * 32 + l32;
#pragma unroll
        for (int reg = 0; reg < 16; reg++) {
            const int row = r0 + (reg & 3) + 8 * (reg >> 2);
            C[(size_t)row * N + c0] = acc1[nt][reg] + acc2[nt][reg] * RINV;
        }
    }
}

// ---------------------------------------------------------------------------
// Attention. qkv layout: [b*S+s][3072], q at h*64+d, k at +1024, v at +2048
// Fused mid kernel: [0,1024) Wout split | [1024,9216) per-position sums |
// [9216,9728) kv chunk totals.
// ---------------------------------------------------------------------------
__global__ __launch_bounds__(256) void k_mid(
    const float* __restrict__ Wout,
    unsigned short* __restrict__ Wouth, unsigned short* __restrict__ Woutm,
    const float* __restrict__ qkv,
    float* __restrict__ SQB, float* __restrict__ SK, float* __restrict__ KVC)
{
    const int blk = blockIdx.x;
    if (blk < 1024) {
        int i = blk * 256 + threadIdx.x;
        split2x4(((const float4*)Wout)[i], Wouth, Woutm, i);
        return;
    }
    if (blk < 9216) {
        const int lane = threadIdx.x & 63;
        const int pos  = (blk - 1024) * 4 + (threadIdx.x >> 6);
        const int bh = pos >> 10, s = pos & 1023;
        const int b = bh >> 4, h = bh & 15;
        const float* base = qkv + (size_t)(b * SEQ + s) * E3D + h * DHEAD + lane;
        float xq = clampx(base[0]);
        float xk = clampx(base[1024]);
        float Tq[6], Tk[6];
        cheb5(xq, Tq); cheb5(xk, Tk);
        const float BETA[5] = {BETA1, BETA2, BETA3, BETA4, BETA5};
#pragma unroll
        for (int p = 1; p <= 5; p++) {
            float sq = wave_sum(Tq[p]);
            float sk = wave_sum(Tk[p]);
            if (lane == 0) {
                SQB[(size_t)pos * 5 + p - 1] = sq * BETA[p - 1];
                SK[(size_t)pos * 5 + p - 1]  = sk;
            }
        }
        return;
    }
    {
        const int lane = threadIdx.x & 63;
        const int cid = (blk - 9216) * 4 + (threadIdx.x >> 6);
        const int bh = cid >> 6, chunk = cid & 63;
        const int b = bh >> 4, h = bh & 15;
        const float* kb = qkv + (size_t)(b * SEQ + chunk * CHUNK) * E3D + 1024 + h * DHEAD + lane;
        float kv[5] = {0.f, 0.f, 0.f, 0.f, 0.f};
#pragma unroll
        for (int i = 0; i < CHUNK; i++) {
            const float* row = kb + (size_t)i * E3D;
            float xk = clampx(row[0]);
            float v = row[1024];
            float T[6]; cheb5(xk, T);
#pragma unroll
            for (int p = 1; p <= 5; p++) kv[p - 1] += T[p] * v;
        }
#pragma unroll
        for (int p = 0; p < 5; p++) KVC[((size_t)cid * 5 + p) * 64 + lane] = kv[p];
    }
}

// Fused prefixes: (A) exclusive prefix over chunks of KVC in place (register
// preload -> independent loads); (B) SK chunk sums + exclusive prefix -> SKP.
__global__ __launch_bounds__(320) void k_prefix(float* __restrict__ KVC,
                                                const float* __restrict__ SK,
                                                float* __restrict__ SKP)
{
    __shared__ float csum[NCHUNK * 5];
    const int bh = blockIdx.x;
    const int t = threadIdx.x;   // 0..319, component = p*64+d
    float v[NCHUNK];
    const size_t base = (size_t)bh * NCHUNK * 320 + t;
#pragma unroll
    for (int c = 0; c < NCHUNK; c++) v[c] = KVC[base + (size_t)c * 320];
    float run = 0.f;
#pragma unroll
    for (int c = 0; c < NCHUNK; c++) {
        KVC[base + (size_t)c * 320] = run;
        run += v[c];
    }
    {
        const int chunk = t / 5, p = t % 5;
        const float* sb = SK + ((size_t)bh * SEQ + chunk * CHUNK) * 5 + p;
        float s = 0.f;
#pragma unroll
        for (int i = 0; i < CHUNK; i++) s += sb[i * 5];
        csum[chunk * 5 + p] = s;
    }
    __syncthreads();
    if (t < 5) {
        float run2 = 0.f;
        for (int c = 0; c < NCHUNK; c++) {
            SKP[((size_t)bh * NCHUNK + c) * 5 + t] = run2;
            run2 += csum[c * 5 + t];
        }
    }
}

// Fused den + output. One wave per chunk (4 waves/block). Lane = d.
// Writes out_h directly as fp16 2-level split (GEMM2 A operand).
__global__ __launch_bounds__(256) void k_out(const float* __restrict__ qkv,
                                             const float* __restrict__ KVC,
                                             const float* __restrict__ SK,
                                             const float* __restrict__ SKP,
                                             const float* __restrict__ SQB,
                                             unsigned short* __restrict__ OH,
                                             unsigned short* __restrict__ OM)
{
    const int lane = threadIdx.x & 63;
    const int cid = blockIdx.x * 4 + (threadIdx.x >> 6);
    const int bh = cid >> 6, chunk = cid & 63;
    const int b = bh >> 4, h = bh & 15;
    const float BETA[5] = {BETA1, BETA2, BETA3, BETA4, BETA5};

    const int li = lane & 15;
    const int pos = bh * SEQ + chunk * CHUNK + li;
    float den_r = 0.f;
#pragma unroll
    for (int p = 0; p < 5; p++) {
        float v = SK[(size_t)pos * 5 + p];
#pragma unroll
        for (int off = 1; off < 16; off <<= 1) {
            float n = __shfl_up(v, off, 64);
            if (li >= off) v += n;
        }
        den_r += SQB[(size_t)pos * 5 + p] * (SKP[((size_t)bh * NCHUNK + chunk) * 5 + p] + v);
    }

    float kv[5];
#pragma unroll
    for (int p = 0; p < 5; p++) kv[p] = KVC[((size_t)cid * 5 + p) * 64 + lane];

    const float* qb = qkv + (size_t)(b * SEQ + chunk * CHUNK) * E3D + h * DHEAD + lane;
    size_t obase = (size_t)(b * SEQ + chunk * CHUNK) * DMODEL + h * DHEAD + lane;
#pragma unroll
    for (int i = 0; i < CHUNK; i++) {
        const float* row = qb + (size_t)i * E3D;
        float xq = clampx(row[0]);
        float xk = clampx(row[1024]);
        float v = row[2048];
        float Tk_[6]; cheb5(xk, Tk_);
#pragma unroll
        for (int p = 1; p <= 5; p++) kv[p - 1] += Tk_[p] * v;
        float Tq_[6]; cheb5(xq, Tq_);
        float num = 0.f;
#pragma unroll
        for (int p = 1; p <= 5; p++) num += BETA[p - 1] * Tq_[p] * kv[p - 1];
        float d = __shfl(den_r, i, 64);
        float val = num / (d + 1e-7f);
        unsigned short hh, mm;
        split2(val, &hh, &mm);
        size_t oi = obase + (size_t)i * DMODEL;
        OH[oi] = hh; OM[oi] = mm;
    }
}

// ---------------------------------------------------------------------------

extern "C" void kernel_launch(void* const* d_in, const int* in_sizes, int n_in,
                              void* d_out, int out_size, void* d_ws, size_t ws_size,
                              hipStream_t stream)
{
    const float* x    = (const float*)d_in[0];  // (2,1024,1024)
    const float* Win  = (const float*)d_in[1];  // (3072,1024)
    const float* Wout = (const float*)d_in[2];  // (1024,1024)
    float* out = (float*)d_out;                 // (2,1024,1024)
    char* ws = (char*)d_ws;

    // workspace layout (byte offsets)
    float* QKV = (float*)(ws + 0);                              // 25,165,824 B
    unsigned short* Xh   = (unsigned short*)(ws + 25165824);    //  4,194,304 each
    unsigned short* Xm   = (unsigned short*)(ws + 29360128);
    unsigned short* Winh = (unsigned short*)(ws + 33554432);    //  6,291,456 each
    unsigned short* Winm = (unsigned short*)(ws + 39845888);    // end 46,137,344
    // After GEMM1, X/Win splits die -> reuse regions:
    float* SQB = (float*)(ws + 25165824);   // 655,360
    float* SK  = (float*)(ws + 25821184);   // 655,360
    float* SKP = (float*)(ws + 26476544);   //  40,960
    float* KVC = (float*)(ws + 26517504);   // 2,621,440 (end 29,138,944)
    unsigned short* OHh   = (unsigned short*)(ws + 33554432);   // 4,194,304 each
    unsigned short* OHm   = (unsigned short*)(ws + 37748736);
    unsigned short* Wouth = (unsigned short*)(ws + 41943040);   // 2,097,152 each
    unsigned short* Woutm = (unsigned short*)(ws + 44040192);   // end 46,137,344

    // split x + Win (one launch)
    k_splitall<<<5120, 256, 0, stream>>>(x, Win, Xh, Xm, Winh, Winm);

    // 1) QKV projection (M=2048, N=3072, K=1024): 64x192 tiles -> 512 blocks (2/CU)
    gemm_w32<192><<<dim3(16, 32), 256, 0, stream>>>(Xh, Xm, Winh, Winm,
                                                    QKV, BATCH * SEQ, E3D, DMODEL);

    // 2) Wout split + per-position sums + kv chunk totals (one launch)
    k_mid<<<9728, 256, 0, stream>>>(Wout, Wouth, Woutm, QKV, SQB, SK, KVC);

    // 3) prefixes
    k_prefix<<<BATCH * NHEADS, 320, 0, stream>>>(KVC, SK, SKP);

    // 4) den + output (writes out_h as fp16 split)
    k_out<<<512, 256, 0, stream>>>(QKV, KVC, SK, SKP, SQB, OHh, OHm);

    // 5) output projection (M=2048, N=1024, K=1024): 64x64 tiles -> 512 blocks (2/CU)
    gemm_w32<64><<<dim3(16, 32), 256, 0, stream>>>(OHh, OHm, Wouth, Woutm,
                                                   out, BATCH * SEQ, DMODEL, DMODEL);
}